// Round 2
// baseline (10877.768 us; speedup 1.0000x reference)
//
#include <hip/hip_runtime.h>

#define TY 32

// ---------- bf16 helpers ----------
__device__ __forceinline__ float blo(unsigned u){ return __uint_as_float(u << 16); }
__device__ __forceinline__ float bhi(unsigned u){ return __uint_as_float(u & 0xffff0000u); }
__device__ __forceinline__ float b2f(unsigned short h){ return __uint_as_float(((unsigned)h) << 16); }
__device__ __forceinline__ unsigned short f2b(float f){
    unsigned u = __float_as_uint(f);
    u += 0x7fffu + ((u >> 16) & 1u);   // RNE
    return (unsigned short)(u >> 16);
}
__device__ __forceinline__ float fast_tanh(float x){
    float ax = fabsf(x);
    float e  = __expf(-2.0f * ax);
    float t  = __fdividef(1.0f - e, 1.0f + e);
    return copysignf(t, x);
}
// cheaper tanh for the attention score loop only: 1 - 2/(e^{2x}+1)
__device__ __forceinline__ float fast_tanh2(float x){
    float E = __expf(2.0f * x);
    return 1.0f - __fdividef(2.0f, E + 1.0f);
}
__device__ __forceinline__ float fast_sigmoid(float x){
    return __fdividef(1.0f, 1.0f + __expf(-x));
}
__device__ __forceinline__ void stf_rt(bool bf, void* p, size_t i, float v){
    if (bf) ((unsigned short*)p)[i] = f2b(v);
    else    ((float*)p)[i] = v;
}
__device__ __forceinline__ void unpack16(uint4 a, uint4 b, float* o){
    o[0]=blo(a.x); o[1]=bhi(a.x); o[2]=blo(a.y); o[3]=bhi(a.y);
    o[4]=blo(a.z); o[5]=bhi(a.z); o[6]=blo(a.w); o[7]=bhi(a.w);
    o[8]=blo(b.x); o[9]=bhi(b.x); o[10]=blo(b.y); o[11]=bhi(b.y);
    o[12]=blo(b.z); o[13]=bhi(b.z); o[14]=blo(b.w); o[15]=bhi(b.w);
}

// ---------- dtype detection + counter init ----------
__global__ void detect_k(const unsigned* __restrict__ xm, int* __restrict__ flag,
                         int* __restrict__ cnt){
    cnt[threadIdx.x] = 0;
    if (threadIdx.x == 0 && blockIdx.x == 0)
        *flag = (xm[0] == 0x3F803F80u) ? 1 : 0;   // bf16 pair (1,1) vs fp32 1.0
}

// ---------- cast native -> fp32 (both dtypes; exact) ----------
__global__ __launch_bounds__(256) void castf_k(const int* __restrict__ flag,
                                               const void* __restrict__ src,
                                               float* __restrict__ dst, int n){
    int i = blockIdx.x * 256 + threadIdx.x;
    if (i < n) dst[i] = (*flag) ? b2f(((const unsigned short*)src)[i]) : ((const float*)src)[i];
}

// ---------- cast fp32 -> bf16 (skips when input already bf16); n8 = n/8 ----------
__global__ __launch_bounds__(256) void castb_k(const int* __restrict__ flag,
                                               const void* __restrict__ src,
                                               unsigned short* __restrict__ dst, long long n8){
    if (*flag) return;
    const float* s = (const float*)src;
    long long i = (long long)blockIdx.x * 256 + threadIdx.x;
    long long stride = (long long)gridDim.x * 256;
    for (; i < n8; i += stride){
        const float* p = s + i * 8;
        float4 a = *(const float4*)p, b = *(const float4*)(p + 4);
        uint4 o;
        o.x = (unsigned)f2b(a.x) | ((unsigned)f2b(a.y) << 16);
        o.y = (unsigned)f2b(a.z) | ((unsigned)f2b(a.w) << 16);
        o.z = (unsigned)f2b(b.x) | ((unsigned)f2b(b.y) << 16);
        o.w = (unsigned)f2b(b.z) | ((unsigned)f2b(b.w) << 16);
        *(uint4*)(dst + i * 8) = o;
    }
}

// ---------- staging load: 8 elems -> packed bf16 uint4 ----------
__device__ __forceinline__ uint4 ld8s(bool bf, const void* __restrict__ nat,
                                      const unsigned short* __restrict__ alt, size_t i){
    if (bf)  return *(const uint4*)((const unsigned short*)nat + i);
    if (alt) return *(const uint4*)(alt + i);
    const float* f = (const float*)nat;
    float4 x = *(const float4*)(f + i), y = *(const float4*)(f + i + 4);
    uint4 r;
    r.x = (unsigned)f2b(x.x) | ((unsigned)f2b(x.y) << 16);
    r.y = (unsigned)f2b(x.z) | ((unsigned)f2b(x.w) << 16);
    r.z = (unsigned)f2b(y.x) | ((unsigned)f2b(y.y) << 16);
    r.w = (unsigned)f2b(y.z) | ((unsigned)f2b(y.w) << 16);
    return r;
}

// ---------- MFMA GEMM: out[M,N] = A[M,K] @ Wt[N,K]^T + bias[N] ----------
typedef short short8 __attribute__((ext_vector_type(8)));
typedef float f32x4  __attribute__((ext_vector_type(4)));

template<bool OB>
__global__ __launch_bounds__(256) void gemm_k(
    const int* __restrict__ flag,
    const void* __restrict__ Anat, const unsigned short* __restrict__ Abf,
    const void* __restrict__ Wnat, const unsigned short* __restrict__ Wbf,
    const float* __restrict__ bias, void* __restrict__ out,
    int N, int K)
{
    const bool bf = (*flag != 0);
    __shared__ __align__(16) unsigned short As[128 * 32];
    __shared__ __align__(16) unsigned short Bs[128 * 32];
    const int tid  = threadIdx.x;
    const int bm   = blockIdx.x, bn = blockIdx.y;
    const int wave = tid >> 6, lane = tid & 63;
    const int wm   = wave >> 1, wn = wave & 1;
    const int q    = lane >> 4, r = lane & 15;
    const int lrow = tid >> 2, lk = (tid & 3) * 8;

    f32x4 acc[4][4];
#pragma unroll
    for (int i = 0; i < 4; i++)
#pragma unroll
        for (int j = 0; j < 4; j++) acc[i][j] = (f32x4){0.f, 0.f, 0.f, 0.f};

    const size_t abase = (size_t)(bm * 128 + lrow) * K + lk;
    const size_t bbase = (size_t)(bn * 128 + lrow) * K + lk;

    for (int kt = 0; kt < K; kt += 32) {
        uint4 va0 = ld8s(bf, Anat, Abf, abase + kt);
        uint4 va1 = ld8s(bf, Anat, Abf, abase + (size_t)64 * K + kt);
        uint4 vb0 = ld8s(bf, Wnat, Wbf, bbase + kt);
        uint4 vb1 = ld8s(bf, Wnat, Wbf, bbase + (size_t)64 * K + kt);
        __syncthreads();
        *(uint4*)&As[lrow * 32 + lk]        = va0;
        *(uint4*)&As[(lrow + 64) * 32 + lk] = va1;
        *(uint4*)&Bs[lrow * 32 + lk]        = vb0;
        *(uint4*)&Bs[(lrow + 64) * 32 + lk] = vb1;
        __syncthreads();
        short8 af[4], bfr[4];
#pragma unroll
        for (int i = 0; i < 4; i++) af[i]  = *(const short8*)&As[(wm * 64 + i * 16 + r) * 32 + q * 8];
#pragma unroll
        for (int j = 0; j < 4; j++) bfr[j] = *(const short8*)&Bs[(wn * 64 + j * 16 + r) * 32 + q * 8];
#pragma unroll
        for (int i = 0; i < 4; i++)
#pragma unroll
            for (int j = 0; j < 4; j++)
                acc[i][j] = __builtin_amdgcn_mfma_f32_16x16x32_bf16(af[i], bfr[j], acc[i][j], 0, 0, 0);
    }
#pragma unroll
    for (int j = 0; j < 4; j++) {
        const int col = bn * 128 + wn * 64 + j * 16 + r;
        const float bv = bias ? bias[col] : 0.0f;
#pragma unroll
        for (int i = 0; i < 4; i++) {
            const int row0 = bm * 128 + wm * 64 + i * 16 + q * 4;
#pragma unroll
            for (int g = 0; g < 4; g++) {
                const size_t oi = (size_t)(row0 + g) * N + col;
                if (OB) ((unsigned short*)out)[oi] = f2b(acc[i][j][g] + bv);
                else    ((float*)out)[oi] = acc[i][j][g] + bv;
            }
        }
    }
}

// ---------- split-K fp32 dot: lane handles k = i*16 + ks*4 + 0..3 ----------
// a/w pre-offset by ks*4; NI = K/16 iterations of stride 16 floats.
template<int NI>
__device__ __forceinline__ float dot4s(const float* __restrict__ a, const float* __restrict__ w){
    float s0 = 0.f, s1 = 0.f, s2 = 0.f, s3 = 0.f;
#pragma unroll 8
    for (int i = 0; i < NI; i++){
        float4 wv = *(const float4*)(w + i * 16);
        float4 av = *(const float4*)(a + i * 16);
        s0 += av.x * wv.x;
        s1 += av.y * wv.y;
        s2 += av.z * wv.z;
        s3 += av.w * wv.w;
    }
    return (s0 + s1) + (s2 + s3);
}

// ---------- step 1: tmp1 = sigmoid(h@U^T + x_t); rhp = h*r1, u1 ----------
// grid (64, 16): block = 4 b-rows x 16 n-cols, 4-lane split-K per output.
__global__ __launch_bounds__(256) void gate1_k(
    const float* __restrict__ h, const float* __restrict__ U,
    const float* __restrict__ xt,
    float* __restrict__ rhp, float* __restrict__ u1)
{
    __shared__ __align__(16) float lA[4 * 516];
    const int tid = threadIdx.x;
    const int ks = tid & 3, g = tid >> 2;
    const int bl = g >> 4, nl = g & 15;
    const int b = blockIdx.y * 4 + bl;
    const int n = blockIdx.x * 16 + nl;
    const float* src = h + (size_t)blockIdx.y * 4 * 512;
    for (int idx = tid; idx < 4 * 512; idx += 256) lA[(idx >> 9) * 516 + (idx & 511)] = src[idx];
    __syncthreads();
    const float* a = lA + bl * 516;
    float s = dot4s<32>(a + ks * 4, U + (size_t)n * 512 + ks * 4);
    s += __shfl_xor(s, 1);
    s += __shfl_xor(s, 2);
    if (ks == 0){
        s += xt[(size_t)b * 1024 + n];
        float v = fast_sigmoid(s);
        if (n < 512) rhp[b * 512 + n] = a[n] * v;
        else         u1[b * 512 + (n - 512)] = v;
    }
}

// ---------- step 2: h1 = blend(tanh(rhp@Ux^T + xx_t)) ----------
// grid (32, 16)
__global__ __launch_bounds__(256) void h1_k(
    const float* __restrict__ rhp, const float* __restrict__ Ux,
    const float* __restrict__ xxt, const float* __restrict__ u1,
    const float* __restrict__ h, const float* __restrict__ ymf, int t,
    float* __restrict__ h1)
{
    __shared__ __align__(16) float lA[4 * 516];
    const int tid = threadIdx.x;
    const int ks = tid & 3, g = tid >> 2;
    const int bl = g >> 4, nl = g & 15;
    const int b = blockIdx.y * 4 + bl;
    const int n = blockIdx.x * 16 + nl;
    const float* src = rhp + (size_t)blockIdx.y * 4 * 512;
    for (int idx = tid; idx < 4 * 512; idx += 256) lA[(idx >> 9) * 516 + (idx & 511)] = src[idx];
    __syncthreads();
    float s = dot4s<32>(lA + bl * 516 + ks * 4, Ux + (size_t)n * 512 + ks * 4);
    s += __shfl_xor(s, 1);
    s += __shfl_xor(s, 2);
    if (ks == 0){
        s += xxt[(size_t)b * 512 + n];
        float th  = fast_tanh(s);
        float u1v = u1[b * 512 + n];
        float hp  = h[b * 512 + n];
        float v   = u1v * hp + (1.f - u1v) * th;
        float ymv = ymf[t * 64 + b];
        h1[b * 512 + n] = ymv * v + (1.f - ymv) * hp;
    }
}

// ---------- step 3: hatt(fp32) = h1 @ W_comb_att^T ----------
// grid (64, 16)
__global__ __launch_bounds__(256) void hatt_k(
    const float* __restrict__ h1, const float* __restrict__ Wcomb,
    float* __restrict__ hatt)
{
    __shared__ __align__(16) float lA[4 * 516];
    const int tid = threadIdx.x;
    const int ks = tid & 3, g = tid >> 2;
    const int bl = g >> 4, nl = g & 15;
    const int b = blockIdx.y * 4 + bl;
    const int n = blockIdx.x * 16 + nl;
    const float* src = h1 + (size_t)blockIdx.y * 4 * 512;
    for (int idx = tid; idx < 4 * 512; idx += 256) lA[(idx >> 9) * 516 + (idx & 511)] = src[idx];
    __syncthreads();
    float s = dot4s<32>(lA + bl * 516 + ks * 4, Wcomb + (size_t)n * 512 + ks * 4);
    s += __shfl_xor(s, 1);
    s += __shfl_xor(s, 2);
    if (ks == 0) hatt[b * 1024 + n] = s;
}

// ---------- fused attention: scores + online softmax + watt@context partials
//            + last-block-done combine (replaces attnc_k) ----------
__global__ __launch_bounds__(256) void attn_k(
    const int* __restrict__ flag,
    const unsigned short* __restrict__ pctx,   // [Tx*B, 1024] bf16
    const float* __restrict__ hatt,            // [B, 1024] fp32
    const float* __restrict__ Uattf,           // [1024] fp32
    const float* __restrict__ xmf,             // [Tx*B] fp32
    const void* __restrict__ ctxnat, const unsigned short* __restrict__ ctxbf,
    float* __restrict__ pm, float* __restrict__ pl, float* __restrict__ pacc,
    float* __restrict__ atted, void* __restrict__ out, int t,
    int* __restrict__ cnt)
{
    const bool bf = (*flag != 0);
    const unsigned short* cb = bf ? (const unsigned short*)ctxnat : ctxbf;
    const int chunk = blockIdx.x;    // 0..15
    const int b     = blockIdx.y;    // 0..63
    const int tid   = threadIdx.x;
    const int wave  = tid >> 6, lane = tid & 63;
    const int c0    = lane * 16;

    float hv[16], uv[16];
    {
        const float* hp = hatt + b * 1024 + c0;
        const float* up = Uattf + c0;
#pragma unroll
        for (int j = 0; j < 16; j += 4) {
            float4 h4 = *(const float4*)(hp + j);
            float4 u4 = *(const float4*)(up + j);
            hv[j]=h4.x; hv[j+1]=h4.y; hv[j+2]=h4.z; hv[j+3]=h4.w;
            uv[j]=u4.x; uv[j+1]=u4.y; uv[j+2]=u4.z; uv[j+3]=u4.w;
        }
    }

    float m = -1e30f, l = 0.f;
    float acc[16];
#pragma unroll
    for (int j = 0; j < 16; j++) acc[j] = 0.f;

    const int tx0 = chunk * 64 + wave * 16;
#pragma unroll 2
    for (int i = 0; i < 16; i++) {
        const int row = (tx0 + i) * 64 + b;
        const unsigned short* pr = pctx + (size_t)row * 1024 + c0;
        uint4 p0 = *(const uint4*)pr;
        uint4 p1 = *(const uint4*)(pr + 8);
        float pe[16];
        unpack16(p0, p1, pe);
        float s = 0.f;
#pragma unroll
        for (int j = 0; j < 16; j++) s += fast_tanh2(pe[j] + hv[j]) * uv[j];
#pragma unroll
        for (int off = 32; off > 0; off >>= 1) s += __shfl_xor(s, off);
        const float xm = xmf[row];
        s *= xm;
        float e;
        if (s > m) {                   // wave-uniform branch
            float cs = __expf(m - s);
            l *= cs;
#pragma unroll
            for (int j = 0; j < 16; j++) acc[j] *= cs;
            m = s;
            e = xm;
        } else {
            e = __expf(s - m) * xm;
        }
        l += e;
        if (cb) {
            const unsigned short* cr = cb + (size_t)row * 1024 + c0;
            uint4 q0 = *(const uint4*)cr;
            uint4 q1 = *(const uint4*)(cr + 8);
            float ce[16];
            unpack16(q0, q1, ce);
#pragma unroll
            for (int j = 0; j < 16; j++) acc[j] += e * ce[j];
        } else {
            const float* cr = (const float*)ctxnat + (size_t)row * 1024 + c0;
#pragma unroll
            for (int j = 0; j < 16; j += 4) {
                float4 c4 = *(const float4*)(cr + j);
                acc[j]   += e * c4.x; acc[j+1] += e * c4.y;
                acc[j+2] += e * c4.z; acc[j+3] += e * c4.w;
            }
        }
    }

    // cross-wave combine in LDS -> one partial per (b, chunk)
    __shared__ float sm[4], sl[4];
    __shared__ __align__(16) float sacc[4][1024];
    if (lane == 0) { sm[wave] = m; sl[wave] = l; }
#pragma unroll
    for (int j = 0; j < 16; j += 4)
        *(float4*)&sacc[wave][c0 + j] = (float4){acc[j], acc[j+1], acc[j+2], acc[j+3]};
    __syncthreads();
    const float m0 = fmaxf(fmaxf(sm[0], sm[1]), fmaxf(sm[2], sm[3]));
    const float s0e = __expf(sm[0] - m0), s1e = __expf(sm[1] - m0);
    const float s2e = __expf(sm[2] - m0), s3e = __expf(sm[3] - m0);
    const int c = tid * 4;
    float4 a0 = *(const float4*)&sacc[0][c];
    float4 a1 = *(const float4*)&sacc[1][c];
    float4 a2 = *(const float4*)&sacc[2][c];
    float4 a3 = *(const float4*)&sacc[3][c];
    float4 r;
    r.x = a0.x*s0e + a1.x*s1e + a2.x*s2e + a3.x*s3e;
    r.y = a0.y*s0e + a1.y*s1e + a2.y*s2e + a3.y*s3e;
    r.z = a0.z*s0e + a1.z*s1e + a2.z*s2e + a3.z*s3e;
    r.w = a0.w*s0e + a1.w*s1e + a2.w*s2e + a3.w*s3e;
    const int pidx = b * 16 + chunk;
    *(float4*)&pacc[(size_t)pidx * 1024 + c] = r;
    if (tid == 0) {
        pm[pidx] = m0;
        pl[pidx] = sl[0]*s0e + sl[1]*s1e + sl[2]*s2e + sl[3]*s3e;
    }

    // ---- last-block-done combine (device-scope release/acquire) ----
    __threadfence();
    __syncthreads();
    __shared__ int lastFlag;
    if (tid == 0) lastFlag = (atomicAdd(&cnt[b], 1) == 15);
    __syncthreads();
    if (!lastFlag) return;
    __threadfence();   // acquire: invalidate caches before reading peers' partials

    float mstar = -1e30f;
#pragma unroll
    for (int k = 0; k < 16; k++) mstar = fmaxf(mstar, pm[b * 16 + k]);
    float sc[16]; float lt = 0.f;
#pragma unroll
    for (int k = 0; k < 16; k++) {
        sc[k] = __expf(pm[b * 16 + k] - mstar);
        lt += sc[k] * pl[b * 16 + k];
    }
    const float inv = __fdividef(1.0f, lt);
    float4 rr = {0.f, 0.f, 0.f, 0.f};
#pragma unroll
    for (int k = 0; k < 16; k++) {
        float4 a = *(const float4*)&pacc[((size_t)b * 16 + k) * 1024 + c];
        rr.x += sc[k] * a.x; rr.y += sc[k] * a.y;
        rr.z += sc[k] * a.z; rr.w += sc[k] * a.w;
    }
    rr.x *= inv; rr.y *= inv; rr.z *= inv; rr.w *= inv;
    *(float4*)&atted[b * 1024 + c] = rr;
    const size_t o = (size_t)2097152 + (size_t)t * 65536 + (size_t)b * 1024 + c;
    stf_rt(bf, out, o,     rr.x);
    stf_rt(bf, out, o + 1, rr.y);
    stf_rt(bf, out, o + 2, rr.z);
    stf_rt(bf, out, o + 3, rr.w);
    if (tid == 0) cnt[b] = 0;   // reset for next step / graph replay
}

// ---------- step 7: tmp2 = sigmoid(atted@Wc^T + h1@U_nl^T + b_nl) ----------
// grid (64, 16)
__global__ __launch_bounds__(256) void gates2_k(
    const float* __restrict__ atted, const float* __restrict__ Wcf,
    const float* __restrict__ h1, const float* __restrict__ Unlf,
    const float* __restrict__ bnlf,
    float* __restrict__ rh2p, float* __restrict__ u2)
{
    __shared__ __align__(16) float lA1[4 * 1028];
    __shared__ __align__(16) float lA2[4 * 516];
    const int tid = threadIdx.x;
    const int ks = tid & 3, g = tid >> 2;
    const int bl = g >> 4, nl = g & 15;
    const int b = blockIdx.y * 4 + bl;
    const int n = blockIdx.x * 16 + nl;
    const float* s1 = atted + (size_t)blockIdx.y * 4 * 1024;
    for (int idx = tid; idx < 4 * 1024; idx += 256) lA1[(idx >> 10) * 1028 + (idx & 1023)] = s1[idx];
    const float* s2 = h1 + (size_t)blockIdx.y * 4 * 512;
    for (int idx = tid; idx < 4 * 512; idx += 256) lA2[(idx >> 9) * 516 + (idx & 511)] = s2[idx];
    __syncthreads();
    float s = dot4s<64>(lA1 + bl * 1028 + ks * 4, Wcf  + (size_t)n * 1024 + ks * 4)
            + dot4s<32>(lA2 + bl * 516  + ks * 4, Unlf + (size_t)n * 512  + ks * 4);
    s += __shfl_xor(s, 1);
    s += __shfl_xor(s, 2);
    if (ks == 0){
        s += bnlf[n];
        float v = fast_sigmoid(s);
        if (n < 512) rh2p[b * 512 + n] = lA2[bl * 516 + n] * v;
        else         u2[b * 512 + (n - 512)] = v;
    }
}

// ---------- step 8: h2 = blend(tanh(atted@Wcx^T + rh2p@Ux_nl^T + bx_nl)) ----------
// grid (32, 16)
__global__ __launch_bounds__(256) void hfinal_k(
    const int* __restrict__ flag,
    const float* __restrict__ atted, const float* __restrict__ Wcxf,
    const float* __restrict__ rh2p, const float* __restrict__ Uxnlf,
    const float* __restrict__ bxnlf,
    const float* __restrict__ h1, const float* __restrict__ u2,
    const float* __restrict__ ymf, int t,
    float* __restrict__ hnext, void* __restrict__ out)
{
    const bool bf = (*flag != 0);
    __shared__ __align__(16) float lA1[4 * 1028];
    __shared__ __align__(16) float lA2[4 * 516];
    const int tid = threadIdx.x;
    const int ks = tid & 3, g = tid >> 2;
    const int bl = g >> 4, nl = g & 15;
    const int b = blockIdx.y * 4 + bl;
    const int n = blockIdx.x * 16 + nl;
    const float* s1 = atted + (size_t)blockIdx.y * 4 * 1024;
    for (int idx = tid; idx < 4 * 1024; idx += 256) lA1[(idx >> 10) * 1028 + (idx & 1023)] = s1[idx];
    const float* s2 = rh2p + (size_t)blockIdx.y * 4 * 512;
    for (int idx = tid; idx < 4 * 512; idx += 256) lA2[(idx >> 9) * 516 + (idx & 511)] = s2[idx];
    __syncthreads();
    float s = dot4s<64>(lA1 + bl * 1028 + ks * 4, Wcxf  + (size_t)n * 1024 + ks * 4)
            + dot4s<32>(lA2 + bl * 516  + ks * 4, Uxnlf + (size_t)n * 512  + ks * 4);
    s += __shfl_xor(s, 1);
    s += __shfl_xor(s, 2);
    if (ks == 0){
        s += bxnlf[n];
        float hx  = fast_tanh(s);
        float h1v = h1[b * 512 + n];
        float u2v = u2[b * 512 + n];
        float h2  = u2v * h1v + (1.f - u2v) * hx;
        float ymv = ymf[t * 64 + b];
        h2 = ymv * h2 + (1.f - ymv) * h1v;
        hnext[b * 512 + n] = h2;
        stf_rt(bf, out, (size_t)t * 32768 + (size_t)b * 512 + n, h2);
        stf_rt(bf, out, (size_t)1048576 + (size_t)t * 32768 + (size_t)b * 512 + n, h2);
    }
}

// ---------- launcher ----------
extern "C" void kernel_launch(void* const* d_in, const int* in_sizes, int n_in,
                              void* d_out, int out_size, void* d_ws, size_t ws_size,
                              hipStream_t stream)
{
    (void)in_sizes; (void)n_in; (void)out_size;
    const void* y_emb   = d_in[0];
    const void* context = d_in[1];
    const void* init_st = d_in[2];
    const void* x_mask  = d_in[3];
    const void* y_mask  = d_in[4];
    const void* W       = d_in[5];
    const void* U       = d_in[6];
    const void* bvec    = d_in[7];
    const void* Wx      = d_in[8];
    const void* Ux      = d_in[9];
    const void* bx      = d_in[10];
    const void* Wc_att  = d_in[11];
    const void* b_att   = d_in[12];
    const void* W_comb  = d_in[13];
    const void* U_att   = d_in[14];
    const void* U_nl    = d_in[15];
    const void* b_nl    = d_in[16];
    const void* Ux_nl   = d_in[17];
    const void* bx_nl   = d_in[18];
    const void* Wc      = d_in[19];
    const void* Wcx     = d_in[20];

    char* w = (char*)d_ws;
    int* flag = (int*)w;                            w += 256;
    unsigned short* pctx  = (unsigned short*)w;     w += (size_t)65536 * 1024 * 2;
    unsigned short* ybf   = (unsigned short*)w;     w += (size_t)2048 * 512 * 2;
    unsigned short* Wbf   = (unsigned short*)w;     w += (size_t)1024 * 512 * 2;
    unsigned short* Wxbf  = (unsigned short*)w;     w += (size_t)512 * 512 * 2;
    unsigned short* Wcabf = (unsigned short*)w;     w += (size_t)1024 * 1024 * 2;
    float* xbuf   = (float*)w;                      w += (size_t)2048 * 1024 * 4;
    float* xxbuf  = (float*)w;                      w += (size_t)2048 * 512 * 4;
    float* Uf     = (float*)w;                      w += (size_t)1024 * 512 * 4;
    float* Uxf    = (float*)w;                      w += (size_t)512 * 512 * 4;
    float* Wcombf = (float*)w;                      w += (size_t)1024 * 512 * 4;
    float* Unlf   = (float*)w;                      w += (size_t)1024 * 512 * 4;
    float* Uxnlf  = (float*)w;                      w += (size_t)512 * 512 * 4;
    float* Wcf    = (float*)w;                      w += (size_t)1024 * 1024 * 4;
    float* Wcxf   = (float*)w;                      w += (size_t)512 * 1024 * 4;
    float* Uattf  = (float*)w;                      w += 1024 * 4;
    float* xmf    = (float*)w;                      w += 65536 * 4;
    float* ymf    = (float*)w;                      w += 2048 * 4;
    float* battf  = (float*)w;                      w += 1024 * 4;
    float* bvecf  = (float*)w;                      w += 1024 * 4;
    float* bxf    = (float*)w;                      w += 512 * 4;
    float* bnlf   = (float*)w;                      w += 1024 * 4;
    float* bxnlf  = (float*)w;                      w += 512 * 4;
    float* hbuf0  = (float*)w;                      w += 64 * 512 * 4;
    float* hbuf1  = (float*)w;                      w += 64 * 512 * 4;
    float* rhp    = (float*)w;                      w += 64 * 512 * 4;
    float* u1     = (float*)w;                      w += 64 * 512 * 4;
    float* h1     = (float*)w;                      w += 64 * 512 * 4;
    float* rh2p   = (float*)w;                      w += 64 * 512 * 4;
    float* u2     = (float*)w;                      w += 64 * 512 * 4;
    float* hatt   = (float*)w;                      w += 64 * 1024 * 4;
    float* pm     = (float*)w;                      w += 64 * 16 * 4;
    float* pl     = (float*)w;                      w += 64 * 16 * 4;
    float* pacc   = (float*)w;                      w += (size_t)64 * 16 * 1024 * 4;
    float* atted  = (float*)w;                      w += 64 * 1024 * 4;
    int*   cnt    = (int*)w;                        w += 256;
    // optional bf16 copy of context (fp32 path): needs +134.2 MB
    size_t base_bytes = (size_t)(w - (char*)d_ws);
    size_t ctx_bytes  = (size_t)65536 * 1024 * 2;
    unsigned short* ctxbf = nullptr;
    if (ws_size >= base_bytes + ctx_bytes + 4096) ctxbf = (unsigned short*)w;

    detect_k<<<1, 64, 0, stream>>>((const unsigned*)x_mask, flag, cnt);

    // one-time fp32 normalizations (exact in both dtype paths)
    castf_k<<<2048, 256, 0, stream>>>(flag, U,      Uf,     524288);
    castf_k<<<1024, 256, 0, stream>>>(flag, Ux,     Uxf,    262144);
    castf_k<<<2048, 256, 0, stream>>>(flag, W_comb, Wcombf, 524288);
    castf_k<<<2048, 256, 0, stream>>>(flag, U_nl,   Unlf,   524288);
    castf_k<<<1024, 256, 0, stream>>>(flag, Ux_nl,  Uxnlf,  262144);
    castf_k<<<4096, 256, 0, stream>>>(flag, Wc,     Wcf,    1048576);
    castf_k<<<2048, 256, 0, stream>>>(flag, Wcx,    Wcxf,   524288);
    castf_k<<<4,    256, 0, stream>>>(flag, U_att,  Uattf,  1024);
    castf_k<<<256,  256, 0, stream>>>(flag, x_mask, xmf,    65536);
    castf_k<<<8,    256, 0, stream>>>(flag, y_mask, ymf,    2048);
    castf_k<<<4,    256, 0, stream>>>(flag, b_att,  battf,  1024);
    castf_k<<<4,    256, 0, stream>>>(flag, bvec,   bvecf,  1024);
    castf_k<<<2,    256, 0, stream>>>(flag, bx,     bxf,    512);
    castf_k<<<4,    256, 0, stream>>>(flag, b_nl,   bnlf,   1024);
    castf_k<<<2,    256, 0, stream>>>(flag, bx_nl,  bxnlf,  512);
    castf_k<<<128,  256, 0, stream>>>(flag, init_st, hbuf0, 32768);

    // one-time bf16 copies for MFMA staging (no-op when inputs already bf16)
    castb_k<<<512,  256, 0, stream>>>(flag, y_emb,  ybf,   131072);
    castb_k<<<256,  256, 0, stream>>>(flag, W,      Wbf,   65536);
    castb_k<<<128,  256, 0, stream>>>(flag, Wx,     Wxbf,  32768);
    castb_k<<<512,  256, 0, stream>>>(flag, Wc_att, Wcabf, 131072);
    if (ctxbf)
        castb_k<<<8192, 256, 0, stream>>>(flag, context, ctxbf, 8388608);

    // precompute: pctx (bf16), x, xx (fp32)
    gemm_k<true ><<<dim3(512, 8), 256, 0, stream>>>(flag, context, ctxbf, Wc_att, Wcabf, battf, pctx, 1024, 1024);
    gemm_k<false><<<dim3(16, 8),  256, 0, stream>>>(flag, y_emb, ybf, W,  Wbf,  bvecf, xbuf,  1024, 512);
    gemm_k<false><<<dim3(16, 4),  256, 0, stream>>>(flag, y_emb, ybf, Wx, Wxbf, bxf,   xxbuf, 512,  512);

    for (int t = 0; t < TY; t++) {
        float* hp = (t & 1) ? hbuf1 : hbuf0;
        float* hn = (t & 1) ? hbuf0 : hbuf1;
        const float* xt  = xbuf  + (size_t)t * 64 * 1024;
        const float* xxt = xxbuf + (size_t)t * 64 * 512;

        gate1_k <<<dim3(64, 16), 256, 0, stream>>>(hp, Uf, xt, rhp, u1);
        h1_k    <<<dim3(32, 16), 256, 0, stream>>>(rhp, Uxf, xxt, u1, hp, ymf, t, h1);
        hatt_k  <<<dim3(64, 16), 256, 0, stream>>>(h1, Wcombf, hatt);
        attn_k  <<<dim3(16, 64), 256, 0, stream>>>(flag, pctx, hatt, Uattf, xmf, context, ctxbf,
                                                   pm, pl, pacc, atted, d_out, t, cnt);
        gates2_k<<<dim3(64, 16), 256, 0, stream>>>(atted, Wcf, h1, Unlf, bnlf, rh2p, u2);
        hfinal_k<<<dim3(32, 16), 256, 0, stream>>>(flag, atted, Wcxf, rh2p, Uxnlf, bxnlf, h1, u2, ymf, t, hn, d_out);
    }
}

// Round 4
// 4422.034 us; speedup vs baseline: 2.4599x; 2.4599x over previous
//
#include <hip/hip_runtime.h>

#define TY 32

// ---------- bf16 helpers ----------
__device__ __forceinline__ float blo(unsigned u){ return __uint_as_float(u << 16); }
__device__ __forceinline__ float bhi(unsigned u){ return __uint_as_float(u & 0xffff0000u); }
__device__ __forceinline__ float b2f(unsigned short h){ return __uint_as_float(((unsigned)h) << 16); }
__device__ __forceinline__ unsigned short f2b(float f){
    unsigned u = __float_as_uint(f);
    u += 0x7fffu + ((u >> 16) & 1u);   // RNE
    return (unsigned short)(u >> 16);
}
__device__ __forceinline__ float fast_tanh(float x){
    float ax = fabsf(x);
    float e  = __expf(-2.0f * ax);
    float t  = __fdividef(1.0f - e, 1.0f + e);
    return copysignf(t, x);
}
// cheaper tanh for the attention score loop only: 1 - 2/(e^{2x}+1)
__device__ __forceinline__ float fast_tanh2(float x){
    float E = __expf(2.0f * x);
    return 1.0f - __fdividef(2.0f, E + 1.0f);
}
__device__ __forceinline__ float fast_sigmoid(float x){
    return __fdividef(1.0f, 1.0f + __expf(-x));
}
__device__ __forceinline__ void stf_rt(bool bf, void* p, size_t i, float v){
    if (bf) ((unsigned short*)p)[i] = f2b(v);
    else    ((float*)p)[i] = v;
}
__device__ __forceinline__ void unpack16(uint4 a, uint4 b, float* o){
    o[0]=blo(a.x); o[1]=bhi(a.x); o[2]=blo(a.y); o[3]=bhi(a.y);
    o[4]=blo(a.z); o[5]=bhi(a.z); o[6]=blo(a.w); o[7]=bhi(a.w);
    o[8]=blo(b.x); o[9]=bhi(b.x); o[10]=blo(b.y); o[11]=bhi(b.y);
    o[12]=blo(b.z); o[13]=bhi(b.z); o[14]=blo(b.w); o[15]=bhi(b.w);
}

// ---------- dtype detection: x_mask is all ones ----------
__global__ void detect_k(const unsigned* __restrict__ xm, int* __restrict__ flag){
    if (threadIdx.x == 0 && blockIdx.x == 0)
        *flag = (xm[0] == 0x3F803F80u) ? 1 : 0;   // bf16 pair (1,1) vs fp32 1.0
}

// ---------- cast native -> fp32 (both dtypes; exact) ----------
__global__ __launch_bounds__(256) void castf_k(const int* __restrict__ flag,
                                               const void* __restrict__ src,
                                               float* __restrict__ dst, int n){
    int i = blockIdx.x * 256 + threadIdx.x;
    if (i < n) dst[i] = (*flag) ? b2f(((const unsigned short*)src)[i]) : ((const float*)src)[i];
}

// ---------- cast fp32 -> bf16 (skips when input already bf16); n8 = n/8 ----------
__global__ __launch_bounds__(256) void castb_k(const int* __restrict__ flag,
                                               const void* __restrict__ src,
                                               unsigned short* __restrict__ dst, long long n8){
    if (*flag) return;
    const float* s = (const float*)src;
    long long i = (long long)blockIdx.x * 256 + threadIdx.x;
    long long stride = (long long)gridDim.x * 256;
    for (; i < n8; i += stride){
        const float* p = s + i * 8;
        float4 a = *(const float4*)p, b = *(const float4*)(p + 4);
        uint4 o;
        o.x = (unsigned)f2b(a.x) | ((unsigned)f2b(a.y) << 16);
        o.y = (unsigned)f2b(a.z) | ((unsigned)f2b(a.w) << 16);
        o.z = (unsigned)f2b(b.x) | ((unsigned)f2b(b.y) << 16);
        o.w = (unsigned)f2b(b.z) | ((unsigned)f2b(b.w) << 16);
        *(uint4*)(dst + i * 8) = o;
    }
}

// ---------- staging load: 8 elems -> packed bf16 uint4 ----------
__device__ __forceinline__ uint4 ld8s(bool bf, const void* __restrict__ nat,
                                      const unsigned short* __restrict__ alt, size_t i){
    if (bf)  return *(const uint4*)((const unsigned short*)nat + i);
    if (alt) return *(const uint4*)(alt + i);
    const float* f = (const float*)nat;
    float4 x = *(const float4*)(f + i), y = *(const float4*)(f + i + 4);
    uint4 r;
    r.x = (unsigned)f2b(x.x) | ((unsigned)f2b(x.y) << 16);
    r.y = (unsigned)f2b(x.z) | ((unsigned)f2b(x.w) << 16);
    r.z = (unsigned)f2b(y.x) | ((unsigned)f2b(y.y) << 16);
    r.w = (unsigned)f2b(y.z) | ((unsigned)f2b(y.w) << 16);
    return r;
}

// ---------- MFMA GEMM: out[M,N] = A[M,K] @ Wt[N,K]^T + bias[N] ----------
typedef short short8 __attribute__((ext_vector_type(8)));
typedef float f32x4  __attribute__((ext_vector_type(4)));

template<bool OB>
__global__ __launch_bounds__(256) void gemm_k(
    const int* __restrict__ flag,
    const void* __restrict__ Anat, const unsigned short* __restrict__ Abf,
    const void* __restrict__ Wnat, const unsigned short* __restrict__ Wbf,
    const float* __restrict__ bias, void* __restrict__ out,
    int N, int K)
{
    const bool bf = (*flag != 0);
    __shared__ __align__(16) unsigned short As[128 * 32];
    __shared__ __align__(16) unsigned short Bs[128 * 32];
    const int tid  = threadIdx.x;
    const int bm   = blockIdx.x, bn = blockIdx.y;
    const int wave = tid >> 6, lane = tid & 63;
    const int wm   = wave >> 1, wn = wave & 1;
    const int q    = lane >> 4, r = lane & 15;
    const int lrow = tid >> 2, lk = (tid & 3) * 8;

    f32x4 acc[4][4];
#pragma unroll
    for (int i = 0; i < 4; i++)
#pragma unroll
        for (int j = 0; j < 4; j++) acc[i][j] = (f32x4){0.f, 0.f, 0.f, 0.f};

    const size_t abase = (size_t)(bm * 128 + lrow) * K + lk;
    const size_t bbase = (size_t)(bn * 128 + lrow) * K + lk;

    for (int kt = 0; kt < K; kt += 32) {
        uint4 va0 = ld8s(bf, Anat, Abf, abase + kt);
        uint4 va1 = ld8s(bf, Anat, Abf, abase + (size_t)64 * K + kt);
        uint4 vb0 = ld8s(bf, Wnat, Wbf, bbase + kt);
        uint4 vb1 = ld8s(bf, Wnat, Wbf, bbase + (size_t)64 * K + kt);
        __syncthreads();
        *(uint4*)&As[lrow * 32 + lk]        = va0;
        *(uint4*)&As[(lrow + 64) * 32 + lk] = va1;
        *(uint4*)&Bs[lrow * 32 + lk]        = vb0;
        *(uint4*)&Bs[(lrow + 64) * 32 + lk] = vb1;
        __syncthreads();
        short8 af[4], bfr[4];
#pragma unroll
        for (int i = 0; i < 4; i++) af[i]  = *(const short8*)&As[(wm * 64 + i * 16 + r) * 32 + q * 8];
#pragma unroll
        for (int j = 0; j < 4; j++) bfr[j] = *(const short8*)&Bs[(wn * 64 + j * 16 + r) * 32 + q * 8];
#pragma unroll
        for (int i = 0; i < 4; i++)
#pragma unroll
            for (int j = 0; j < 4; j++)
                acc[i][j] = __builtin_amdgcn_mfma_f32_16x16x32_bf16(af[i], bfr[j], acc[i][j], 0, 0, 0);
    }
#pragma unroll
    for (int j = 0; j < 4; j++) {
        const int col = bn * 128 + wn * 64 + j * 16 + r;
        const float bv = bias ? bias[col] : 0.0f;
#pragma unroll
        for (int i = 0; i < 4; i++) {
            const int row0 = bm * 128 + wm * 64 + i * 16 + q * 4;
#pragma unroll
            for (int g = 0; g < 4; g++) {
                const size_t oi = (size_t)(row0 + g) * N + col;
                if (OB) ((unsigned short*)out)[oi] = f2b(acc[i][j][g] + bv);
                else    ((float*)out)[oi] = acc[i][j][g] + bv;
            }
        }
    }
}

// ---------- split-K fp32 dot: lane handles k = i*16 + ks*4 + 0..3 ----------
template<int NI>
__device__ __forceinline__ float dot4s(const float* __restrict__ a, const float* __restrict__ w){
    float s0 = 0.f, s1 = 0.f, s2 = 0.f, s3 = 0.f;
#pragma unroll 8
    for (int i = 0; i < NI; i++){
        float4 wv = *(const float4*)(w + i * 16);
        float4 av = *(const float4*)(a + i * 16);
        s0 += av.x * wv.x;
        s1 += av.y * wv.y;
        s2 += av.z * wv.z;
        s3 += av.w * wv.w;
    }
    return (s0 + s1) + (s2 + s3);
}

// ---------- step 1: tmp1 = sigmoid(h@U^T + x_t); rhp = h*r1, u1 ----------
// grid (64, 16): block = 4 b-rows x 16 n-cols, 4-lane split-K per output.
__global__ __launch_bounds__(256) void gate1_k(
    const float* __restrict__ h, const float* __restrict__ U,
    const float* __restrict__ xt,
    float* __restrict__ rhp, float* __restrict__ u1)
{
    __shared__ __align__(16) float lA[4 * 516];
    const int tid = threadIdx.x;
    const int ks = tid & 3, g = tid >> 2;
    const int bl = g >> 4, nl = g & 15;
    const int b = blockIdx.y * 4 + bl;
    const int n = blockIdx.x * 16 + nl;
    const float* src = h + (size_t)blockIdx.y * 4 * 512;
    for (int idx = tid; idx < 4 * 512; idx += 256) lA[(idx >> 9) * 516 + (idx & 511)] = src[idx];
    __syncthreads();
    const float* a = lA + bl * 516;
    float s = dot4s<32>(a + ks * 4, U + (size_t)n * 512 + ks * 4);
    s += __shfl_xor(s, 1);
    s += __shfl_xor(s, 2);
    if (ks == 0){
        s += xt[(size_t)b * 1024 + n];
        float v = fast_sigmoid(s);
        if (n < 512) rhp[b * 512 + n] = a[n] * v;
        else         u1[b * 512 + (n - 512)] = v;
    }
}

// ---------- step 2: h1 = blend(tanh(rhp@Ux^T + xx_t)) ----------
// grid (32, 16)
__global__ __launch_bounds__(256) void h1_k(
    const float* __restrict__ rhp, const float* __restrict__ Ux,
    const float* __restrict__ xxt, const float* __restrict__ u1,
    const float* __restrict__ h, const float* __restrict__ ymf, int t,
    float* __restrict__ h1)
{
    __shared__ __align__(16) float lA[4 * 516];
    const int tid = threadIdx.x;
    const int ks = tid & 3, g = tid >> 2;
    const int bl = g >> 4, nl = g & 15;
    const int b = blockIdx.y * 4 + bl;
    const int n = blockIdx.x * 16 + nl;
    const float* src = rhp + (size_t)blockIdx.y * 4 * 512;
    for (int idx = tid; idx < 4 * 512; idx += 256) lA[(idx >> 9) * 516 + (idx & 511)] = src[idx];
    __syncthreads();
    float s = dot4s<32>(lA + bl * 516 + ks * 4, Ux + (size_t)n * 512 + ks * 4);
    s += __shfl_xor(s, 1);
    s += __shfl_xor(s, 2);
    if (ks == 0){
        s += xxt[(size_t)b * 512 + n];
        float th  = fast_tanh(s);
        float u1v = u1[b * 512 + n];
        float hp  = h[b * 512 + n];
        float v   = u1v * hp + (1.f - u1v) * th;
        float ymv = ymf[t * 64 + b];
        h1[b * 512 + n] = ymv * v + (1.f - ymv) * hp;
    }
}

// ---------- step 3: hatt(fp32) = h1 @ W_comb_att^T ----------
// grid (64, 16)
__global__ __launch_bounds__(256) void hatt_k(
    const float* __restrict__ h1, const float* __restrict__ Wcomb,
    float* __restrict__ hatt)
{
    __shared__ __align__(16) float lA[4 * 516];
    const int tid = threadIdx.x;
    const int ks = tid & 3, g = tid >> 2;
    const int bl = g >> 4, nl = g & 15;
    const int b = blockIdx.y * 4 + bl;
    const int n = blockIdx.x * 16 + nl;
    const float* src = h1 + (size_t)blockIdx.y * 4 * 512;
    for (int idx = tid; idx < 4 * 512; idx += 256) lA[(idx >> 9) * 516 + (idx & 511)] = src[idx];
    __syncthreads();
    float s = dot4s<32>(lA + bl * 516 + ks * 4, Wcomb + (size_t)n * 512 + ks * 4);
    s += __shfl_xor(s, 1);
    s += __shfl_xor(s, 2);
    if (ks == 0) hatt[b * 1024 + n] = s;
}

// ---------- fused attention: scores + online softmax + watt@context partials ----------
// grid (16 chunks, 64 b), 256 threads = 4 waves, each wave owns 16 tx rows.
__global__ __launch_bounds__(256) void attn_k(
    const int* __restrict__ flag,
    const unsigned short* __restrict__ pctx,   // [Tx*B, 1024] bf16
    const float* __restrict__ hatt,            // [B, 1024] fp32
    const float* __restrict__ Uattf,           // [1024] fp32
    const float* __restrict__ xmf,             // [Tx*B] fp32
    const void* __restrict__ ctxnat, const unsigned short* __restrict__ ctxbf,
    float* __restrict__ pm, float* __restrict__ pl, float* __restrict__ pacc)
{
    const bool bf = (*flag != 0);
    const unsigned short* cb = bf ? (const unsigned short*)ctxnat : ctxbf;
    const int chunk = blockIdx.x;    // 0..15
    const int b     = blockIdx.y;    // 0..63
    const int tid   = threadIdx.x;
    const int wave  = tid >> 6, lane = tid & 63;
    const int c0    = lane * 16;

    float hv[16], uv[16];
    {
        const float* hp = hatt + b * 1024 + c0;
        const float* up = Uattf + c0;
#pragma unroll
        for (int j = 0; j < 16; j += 4) {
            float4 h4 = *(const float4*)(hp + j);
            float4 u4 = *(const float4*)(up + j);
            hv[j]=h4.x; hv[j+1]=h4.y; hv[j+2]=h4.z; hv[j+3]=h4.w;
            uv[j]=u4.x; uv[j+1]=u4.y; uv[j+2]=u4.z; uv[j+3]=u4.w;
        }
    }

    float m = -1e30f, l = 0.f;
    float acc[16];
#pragma unroll
    for (int j = 0; j < 16; j++) acc[j] = 0.f;

    const int tx0 = chunk * 64 + wave * 16;
#pragma unroll 2
    for (int i = 0; i < 16; i++) {
        const int row = (tx0 + i) * 64 + b;
        const unsigned short* pr = pctx + (size_t)row * 1024 + c0;
        uint4 p0 = *(const uint4*)pr;
        uint4 p1 = *(const uint4*)(pr + 8);
        float pe[16];
        unpack16(p0, p1, pe);
        float s = 0.f;
#pragma unroll
        for (int j = 0; j < 16; j++) s += fast_tanh2(pe[j] + hv[j]) * uv[j];
#pragma unroll
        for (int off = 32; off > 0; off >>= 1) s += __shfl_xor(s, off);
        const float xm = xmf[row];
        s *= xm;
        float e;
        if (s > m) {                   // wave-uniform branch
            float cs = __expf(m - s);
            l *= cs;
#pragma unroll
            for (int j = 0; j < 16; j++) acc[j] *= cs;
            m = s;
            e = xm;
        } else {
            e = __expf(s - m) * xm;
        }
        l += e;
        if (cb) {
            const unsigned short* cr = cb + (size_t)row * 1024 + c0;
            uint4 q0 = *(const uint4*)cr;
            uint4 q1 = *(const uint4*)(cr + 8);
            float ce[16];
            unpack16(q0, q1, ce);
#pragma unroll
            for (int j = 0; j < 16; j++) acc[j] += e * ce[j];
        } else {
            const float* cr = (const float*)ctxnat + (size_t)row * 1024 + c0;
#pragma unroll
            for (int j = 0; j < 16; j += 4) {
                float4 c4 = *(const float4*)(cr + j);
                acc[j]   += e * c4.x; acc[j+1] += e * c4.y;
                acc[j+2] += e * c4.z; acc[j+3] += e * c4.w;
            }
        }
    }

    // cross-wave combine in LDS -> one partial per (b, chunk)
    __shared__ float sm[4], sl[4];
    __shared__ __align__(16) float sacc[4][1024];
    if (lane == 0) { sm[wave] = m; sl[wave] = l; }
#pragma unroll
    for (int j = 0; j < 16; j += 4)
        *(float4*)&sacc[wave][c0 + j] = (float4){acc[j], acc[j+1], acc[j+2], acc[j+3]};
    __syncthreads();
    const float m0 = fmaxf(fmaxf(sm[0], sm[1]), fmaxf(sm[2], sm[3]));
    const float s0e = __expf(sm[0] - m0), s1e = __expf(sm[1] - m0);
    const float s2e = __expf(sm[2] - m0), s3e = __expf(sm[3] - m0);
    const int c = tid * 4;
    float4 a0 = *(const float4*)&sacc[0][c];
    float4 a1 = *(const float4*)&sacc[1][c];
    float4 a2 = *(const float4*)&sacc[2][c];
    float4 a3 = *(const float4*)&sacc[3][c];
    float4 r;
    r.x = a0.x*s0e + a1.x*s1e + a2.x*s2e + a3.x*s3e;
    r.y = a0.y*s0e + a1.y*s1e + a2.y*s2e + a3.y*s3e;
    r.z = a0.z*s0e + a1.z*s1e + a2.z*s2e + a3.z*s3e;
    r.w = a0.w*s0e + a1.w*s1e + a2.w*s2e + a3.w*s3e;
    const int pidx = b * 16 + chunk;
    *(float4*)&pacc[(size_t)pidx * 1024 + c] = r;
    if (tid == 0) {
        pm[pidx] = m0;
        pl[pidx] = sl[0]*s0e + sl[1]*s1e + sl[2]*s2e + sl[3]*s3e;
    }
}

// ---------- attention combine: merge 16 chunk partials -> atted (fp32) + atts output ----------
__global__ __launch_bounds__(256) void attnc_k(
    const int* __restrict__ flag,
    const float* __restrict__ pm, const float* __restrict__ pl,
    const float* __restrict__ pacc,
    float* __restrict__ atted, void* __restrict__ out, int t)
{
    const bool bf = (*flag != 0);
    const int b = blockIdx.x, tid = threadIdx.x;
    float mstar = -1e30f;
#pragma unroll
    for (int k = 0; k < 16; k++) mstar = fmaxf(mstar, pm[b * 16 + k]);
    float sc[16]; float lt = 0.f;
#pragma unroll
    for (int k = 0; k < 16; k++) {
        sc[k] = __expf(pm[b * 16 + k] - mstar);
        lt += sc[k] * pl[b * 16 + k];
    }
    const float inv = __fdividef(1.0f, lt);
    const int c = tid * 4;
    float4 r = {0.f, 0.f, 0.f, 0.f};
#pragma unroll
    for (int k = 0; k < 16; k++) {
        float4 a = *(const float4*)&pacc[((size_t)b * 16 + k) * 1024 + c];
        r.x += sc[k] * a.x; r.y += sc[k] * a.y;
        r.z += sc[k] * a.z; r.w += sc[k] * a.w;
    }
    r.x *= inv; r.y *= inv; r.z *= inv; r.w *= inv;
    *(float4*)&atted[b * 1024 + c] = r;
    const size_t o = (size_t)2097152 + (size_t)t * 65536 + (size_t)b * 1024 + c;
    stf_rt(bf, out, o,     r.x);
    stf_rt(bf, out, o + 1, r.y);
    stf_rt(bf, out, o + 2, r.z);
    stf_rt(bf, out, o + 3, r.w);
}

// ---------- step 7: tmp2 = sigmoid(atted@Wc^T + h1@U_nl^T + b_nl) ----------
// grid (64, 16)
__global__ __launch_bounds__(256) void gates2_k(
    const float* __restrict__ atted, const float* __restrict__ Wcf,
    const float* __restrict__ h1, const float* __restrict__ Unlf,
    const float* __restrict__ bnlf,
    float* __restrict__ rh2p, float* __restrict__ u2)
{
    __shared__ __align__(16) float lA1[4 * 1028];
    __shared__ __align__(16) float lA2[4 * 516];
    const int tid = threadIdx.x;
    const int ks = tid & 3, g = tid >> 2;
    const int bl = g >> 4, nl = g & 15;
    const int b = blockIdx.y * 4 + bl;
    const int n = blockIdx.x * 16 + nl;
    const float* s1 = atted + (size_t)blockIdx.y * 4 * 1024;
    for (int idx = tid; idx < 4 * 1024; idx += 256) lA1[(idx >> 10) * 1028 + (idx & 1023)] = s1[idx];
    const float* s2 = h1 + (size_t)blockIdx.y * 4 * 512;
    for (int idx = tid; idx < 4 * 512; idx += 256) lA2[(idx >> 9) * 516 + (idx & 511)] = s2[idx];
    __syncthreads();
    float s = dot4s<64>(lA1 + bl * 1028 + ks * 4, Wcf  + (size_t)n * 1024 + ks * 4)
            + dot4s<32>(lA2 + bl * 516  + ks * 4, Unlf + (size_t)n * 512  + ks * 4);
    s += __shfl_xor(s, 1);
    s += __shfl_xor(s, 2);
    if (ks == 0){
        s += bnlf[n];
        float v = fast_sigmoid(s);
        if (n < 512) rh2p[b * 512 + n] = lA2[bl * 516 + n] * v;
        else         u2[b * 512 + (n - 512)] = v;
    }
}

// ---------- step 8: h2 = blend(tanh(atted@Wcx^T + rh2p@Ux_nl^T + bx_nl)) ----------
// grid (32, 16)
__global__ __launch_bounds__(256) void hfinal_k(
    const int* __restrict__ flag,
    const float* __restrict__ atted, const float* __restrict__ Wcxf,
    const float* __restrict__ rh2p, const float* __restrict__ Uxnlf,
    const float* __restrict__ bxnlf,
    const float* __restrict__ h1, const float* __restrict__ u2,
    const float* __restrict__ ymf, int t,
    float* __restrict__ hnext, void* __restrict__ out)
{
    const bool bf = (*flag != 0);
    __shared__ __align__(16) float lA1[4 * 1028];
    __shared__ __align__(16) float lA2[4 * 516];
    const int tid = threadIdx.x;
    const int ks = tid & 3, g = tid >> 2;
    const int bl = g >> 4, nl = g & 15;
    const int b = blockIdx.y * 4 + bl;
    const int n = blockIdx.x * 16 + nl;
    const float* s1 = atted + (size_t)blockIdx.y * 4 * 1024;
    for (int idx = tid; idx < 4 * 1024; idx += 256) lA1[(idx >> 10) * 1028 + (idx & 1023)] = s1[idx];
    const float* s2 = rh2p + (size_t)blockIdx.y * 4 * 512;
    for (int idx = tid; idx < 4 * 512; idx += 256) lA2[(idx >> 9) * 516 + (idx & 511)] = s2[idx];
    __syncthreads();
    float s = dot4s<64>(lA1 + bl * 1028 + ks * 4, Wcxf  + (size_t)n * 1024 + ks * 4)
            + dot4s<32>(lA2 + bl * 516  + ks * 4, Uxnlf + (size_t)n * 512  + ks * 4);
    s += __shfl_xor(s, 1);
    s += __shfl_xor(s, 2);
    if (ks == 0){
        s += bxnlf[n];
        float hx  = fast_tanh(s);
        float h1v = h1[b * 512 + n];
        float u2v = u2[b * 512 + n];
        float h2  = u2v * h1v + (1.f - u2v) * hx;
        float ymv = ymf[t * 64 + b];
        h2 = ymv * h2 + (1.f - ymv) * h1v;
        hnext[b * 512 + n] = h2;
        stf_rt(bf, out, (size_t)t * 32768 + (size_t)b * 512 + n, h2);
        stf_rt(bf, out, (size_t)1048576 + (size_t)t * 32768 + (size_t)b * 512 + n, h2);
    }
}

// ---------- launcher ----------
extern "C" void kernel_launch(void* const* d_in, const int* in_sizes, int n_in,
                              void* d_out, int out_size, void* d_ws, size_t ws_size,
                              hipStream_t stream)
{
    (void)in_sizes; (void)n_in; (void)out_size;
    const void* y_emb   = d_in[0];
    const void* context = d_in[1];
    const void* init_st = d_in[2];
    const void* x_mask  = d_in[3];
    const void* y_mask  = d_in[4];
    const void* W       = d_in[5];
    const void* U       = d_in[6];
    const void* bvec    = d_in[7];
    const void* Wx      = d_in[8];
    const void* Ux      = d_in[9];
    const void* bx      = d_in[10];
    const void* Wc_att  = d_in[11];
    const void* b_att   = d_in[12];
    const void* W_comb  = d_in[13];
    const void* U_att   = d_in[14];
    const void* U_nl    = d_in[15];
    const void* b_nl    = d_in[16];
    const void* Ux_nl   = d_in[17];
    const void* bx_nl   = d_in[18];
    const void* Wc      = d_in[19];
    const void* Wcx     = d_in[20];

    char* w = (char*)d_ws;
    int* flag = (int*)w;                            w += 256;
    unsigned short* pctx  = (unsigned short*)w;     w += (size_t)65536 * 1024 * 2;
    unsigned short* ybf   = (unsigned short*)w;     w += (size_t)2048 * 512 * 2;
    unsigned short* Wbf   = (unsigned short*)w;     w += (size_t)1024 * 512 * 2;
    unsigned short* Wxbf  = (unsigned short*)w;     w += (size_t)512 * 512 * 2;
    unsigned short* Wcabf = (unsigned short*)w;     w += (size_t)1024 * 1024 * 2;
    float* xbuf   = (float*)w;                      w += (size_t)2048 * 1024 * 4;
    float* xxbuf  = (float*)w;                      w += (size_t)2048 * 512 * 4;
    float* Uf     = (float*)w;                      w += (size_t)1024 * 512 * 4;
    float* Uxf    = (float*)w;                      w += (size_t)512 * 512 * 4;
    float* Wcombf = (float*)w;                      w += (size_t)1024 * 512 * 4;
    float* Unlf   = (float*)w;                      w += (size_t)1024 * 512 * 4;
    float* Uxnlf  = (float*)w;                      w += (size_t)512 * 512 * 4;
    float* Wcf    = (float*)w;                      w += (size_t)1024 * 1024 * 4;
    float* Wcxf   = (float*)w;                      w += (size_t)512 * 1024 * 4;
    float* Uattf  = (float*)w;                      w += 1024 * 4;
    float* xmf    = (float*)w;                      w += 65536 * 4;
    float* ymf    = (float*)w;                      w += 2048 * 4;
    float* battf  = (float*)w;                      w += 1024 * 4;
    float* bvecf  = (float*)w;                      w += 1024 * 4;
    float* bxf    = (float*)w;                      w += 512 * 4;
    float* bnlf   = (float*)w;                      w += 1024 * 4;
    float* bxnlf  = (float*)w;                      w += 512 * 4;
    float* hbuf0  = (float*)w;                      w += 64 * 512 * 4;
    float* hbuf1  = (float*)w;                      w += 64 * 512 * 4;
    float* rhp    = (float*)w;                      w += 64 * 512 * 4;
    float* u1     = (float*)w;                      w += 64 * 512 * 4;
    float* h1     = (float*)w;                      w += 64 * 512 * 4;
    float* rh2p   = (float*)w;                      w += 64 * 512 * 4;
    float* u2     = (float*)w;                      w += 64 * 512 * 4;
    float* hatt   = (float*)w;                      w += 64 * 1024 * 4;
    float* pm     = (float*)w;                      w += 64 * 16 * 4;
    float* pl     = (float*)w;                      w += 64 * 16 * 4;
    float* pacc   = (float*)w;                      w += (size_t)64 * 16 * 1024 * 4;
    float* atted  = (float*)w;                      w += 64 * 1024 * 4;
    // optional bf16 copy of context (fp32 path): needs +134.2 MB
    size_t base_bytes = (size_t)(w - (char*)d_ws);
    size_t ctx_bytes  = (size_t)65536 * 1024 * 2;
    unsigned short* ctxbf = nullptr;
    if (ws_size >= base_bytes + ctx_bytes + 4096) ctxbf = (unsigned short*)w;

    detect_k<<<1, 64, 0, stream>>>((const unsigned*)x_mask, flag);

    // one-time fp32 normalizations (exact in both dtype paths)
    castf_k<<<2048, 256, 0, stream>>>(flag, U,      Uf,     524288);
    castf_k<<<1024, 256, 0, stream>>>(flag, Ux,     Uxf,    262144);
    castf_k<<<2048, 256, 0, stream>>>(flag, W_comb, Wcombf, 524288);
    castf_k<<<2048, 256, 0, stream>>>(flag, U_nl,   Unlf,   524288);
    castf_k<<<1024, 256, 0, stream>>>(flag, Ux_nl,  Uxnlf,  262144);
    castf_k<<<4096, 256, 0, stream>>>(flag, Wc,     Wcf,    1048576);
    castf_k<<<2048, 256, 0, stream>>>(flag, Wcx,    Wcxf,   524288);
    castf_k<<<4,    256, 0, stream>>>(flag, U_att,  Uattf,  1024);
    castf_k<<<256,  256, 0, stream>>>(flag, x_mask, xmf,    65536);
    castf_k<<<8,    256, 0, stream>>>(flag, y_mask, ymf,    2048);
    castf_k<<<4,    256, 0, stream>>>(flag, b_att,  battf,  1024);
    castf_k<<<4,    256, 0, stream>>>(flag, bvec,   bvecf,  1024);
    castf_k<<<2,    256, 0, stream>>>(flag, bx,     bxf,    512);
    castf_k<<<4,    256, 0, stream>>>(flag, b_nl,   bnlf,   1024);
    castf_k<<<2,    256, 0, stream>>>(flag, bx_nl,  bxnlf,  512);
    castf_k<<<128,  256, 0, stream>>>(flag, init_st, hbuf0, 32768);

    // one-time bf16 copies for MFMA staging (no-op when inputs already bf16)
    castb_k<<<512,  256, 0, stream>>>(flag, y_emb,  ybf,   131072);
    castb_k<<<256,  256, 0, stream>>>(flag, W,      Wbf,   65536);
    castb_k<<<128,  256, 0, stream>>>(flag, Wx,     Wxbf,  32768);
    castb_k<<<512,  256, 0, stream>>>(flag, Wc_att, Wcabf, 131072);
    if (ctxbf)
        castb_k<<<8192, 256, 0, stream>>>(flag, context, ctxbf, 8388608);

    // precompute: pctx (bf16), x, xx (fp32)
    gemm_k<true ><<<dim3(512, 8), 256, 0, stream>>>(flag, context, ctxbf, Wc_att, Wcabf, battf, pctx, 1024, 1024);
    gemm_k<false><<<dim3(16, 8),  256, 0, stream>>>(flag, y_emb, ybf, W,  Wbf,  bvecf, xbuf,  1024, 512);
    gemm_k<false><<<dim3(16, 4),  256, 0, stream>>>(flag, y_emb, ybf, Wx, Wxbf, bxf,   xxbuf, 512,  512);

    for (int t = 0; t < TY; t++) {
        float* hp = (t & 1) ? hbuf1 : hbuf0;
        float* hn = (t & 1) ? hbuf0 : hbuf1;
        const float* xt  = xbuf  + (size_t)t * 64 * 1024;
        const float* xxt = xxbuf + (size_t)t * 64 * 512;

        gate1_k <<<dim3(64, 16), 256, 0, stream>>>(hp, Uf, xt, rhp, u1);
        h1_k    <<<dim3(32, 16), 256, 0, stream>>>(rhp, Uxf, xxt, u1, hp, ymf, t, h1);
        hatt_k  <<<dim3(64, 16), 256, 0, stream>>>(h1, Wcombf, hatt);
        attn_k  <<<dim3(16, 64), 256, 0, stream>>>(flag, pctx, hatt, Uattf, xmf, context, ctxbf,
                                                   pm, pl, pacc);
        attnc_k <<<64,           256, 0, stream>>>(flag, pm, pl, pacc, atted, d_out, t);
        gates2_k<<<dim3(64, 16), 256, 0, stream>>>(atted, Wcf, h1, Unlf, bnlf, rh2p, u2);
        hfinal_k<<<dim3(32, 16), 256, 0, stream>>>(flag, atted, Wcxf, rh2p, Uxnlf, bxnlf, h1, u2, ymf, t, hn, d_out);
    }
}